// Round 9
// baseline (423.864 us; speedup 1.0000x reference)
//
#include <hip/hip_runtime.h>
#include <hip/hip_fp16.h>

typedef int v4i __attribute__((ext_vector_type(4)));

#define AS1C(p) ((const __attribute__((address_space(1))) void*)(p))
#define AS3(p)  ((__attribute__((address_space(3))) void*)(p))

// ---------------------------------------------------------------------------
// 64x256 int8 GEMM tile, C = A[M,K]*B[N,K]^T, 4 waves (1M x 4N), each wave
// owns 64 rows x 64 cols (4mi x 4ni of 16x16), mfma_i32_16x16x64_i8, BK=64B.
// Double-buffered LDS (40KB) -> 4 blocks/CU (160KB): deep TLP hides the
// per-step __syncthreads drain (r8 evidence: simple-sync + TLP beats every
// explicit pipeline tried). Higher intensity than 128^2: 20KB staged per
// K-step for the same 16 MFMA/wave. 16B-slot XOR swizzle (global-side, with
// matching reader involution). Column-chunked bijective XCD swizzle.
// EPI 0: fc1 (dequant+bias -> fp16 -> GELU -> gout fp16 + atomicMax amax)
// EPI 1: fc2 (dequant with fp16(amax/127)+bias -> fp16-rounded f32 out)
// ---------------------------------------------------------------------------
template <int EPI>
__launch_bounds__(256, 4)
__global__ void gemm_w(const signed char* __restrict__ A, const signed char* __restrict__ Bw,
                       int M, int N, int K,
                       const float* __restrict__ scale_tok, const float* __restrict__ wsc,
                       const float* __restrict__ bias,
                       __half* __restrict__ gout, unsigned int* __restrict__ amax,
                       float* __restrict__ fout) {
  __shared__ __align__(16) char smem[2][20480];   // per buf: A 4KB | B 16KB
  const int tid = threadIdx.x;
  const int lane = tid & 63, wave = tid >> 6;     // wave = waven (1M x 4N)
  const int lh = lane & 15, sseg = lane >> 4;

  // column-chunked bijective XCD swizzle: consecutive lid share n0 (B panel)
  const int gy = gridDim.y;
  int lid;
  {
    const int o = blockIdx.y * gridDim.x + blockIdx.x;
    const int nwg = gridDim.x * gy;
    const int q = nwg >> 3, r = nwg & 7;
    const int x = o & 7, p = o >> 3;
    lid = (x < r ? x * (q + 1) : r * (q + 1) + (x - r) * q) + p;
  }
  const long long t0 = (long long)(lid % gy) * 64;
  const long long n0 = (long long)(lid / gy) * 256;
  const int nk = K >> 6;
  const long long Mm1 = M - 1, Nm1 = N - 1;

  // ---- staging pointers: A chunk `wave` (1/wave) + B chunks wave*4+i (4/wave)
  const int lr4 = lane >> 2, slot = lane & 3;
  const signed char* spA;
  {
    const int rloc = wave * 16 + lr4;                 // tile-local row 0-63
    const int gslot = (slot ^ ((rloc >> 1) & 3)) << 4;
    long long gr = t0 + rloc; if (gr > Mm1) gr = Mm1;
    spA = A + gr * (long long)K + gslot;
  }
  const signed char* spB[4];
#pragma unroll
  for (int i = 0; i < 4; ++i) {
    const int cb = wave * 4 + i;
    const int rloc = cb * 16 + lr4;                   // tile-local row 0-255
    const int gslot = (slot ^ ((rloc >> 1) & 3)) << 4;
    long long gr = n0 + rloc; if (gr > Nm1) gr = Nm1;
    spB[i] = Bw + gr * (long long)K + gslot;
  }
  const int dstA = wave * 1024;

#define STAGE(bi) do { \
    __builtin_amdgcn_global_load_lds(AS1C(spA), AS3(&smem[bi][dstA]), 16, 0, 0); spA += 64; \
    _Pragma("unroll") \
    for (int i = 0; i < 4; ++i) { \
      __builtin_amdgcn_global_load_lds(AS1C(spB[i]), AS3(&smem[bi][4096 + (wave * 4 + i) * 1024]), 16, 0, 0); \
      spB[i] += 64; \
    } \
  } while (0)

  // ---- reader offsets (same XOR involution; 16-row strides preserve it)
  const int xs = ((sseg ^ ((lh >> 1) & 3)) << 4);
  const int offA = lh * 64 + xs;                       // + mi*1024
  const int offB = 4096 + wave * 4096 + lh * 64 + xs;  // + ni*1024

  v4i acc[4][4] = {};

  STAGE(0);
  __syncthreads();

  int cur = 0;
  for (int kt = 0; kt < nk; ++kt) {
    if (kt + 1 < nk) STAGE(cur ^ 1);
    v4i af[4], bf[4];
#pragma unroll
    for (int mi = 0; mi < 4; ++mi) af[mi] = *(const v4i*)&smem[cur][offA + mi * 1024];
#pragma unroll
    for (int ni = 0; ni < 4; ++ni) bf[ni] = *(const v4i*)&smem[cur][offB + ni * 1024];
#pragma unroll
    for (int mi = 0; mi < 4; ++mi)
#pragma unroll
      for (int ni = 0; ni < 4; ++ni)
        acc[mi][ni] = __builtin_amdgcn_mfma_i32_16x16x64_i8(af[mi], bf[ni], acc[mi][ni], 0, 0, 0);
    __syncthreads();
    cur ^= 1;
  }
#undef STAGE

  // ---- epilogue (all waves share rows; each owns a 64-col quarter)
  long long cidx[4]; float w4[4], bi4[4]; bool cok[4];
#pragma unroll
  for (int ni = 0; ni < 4; ++ni) {
    cidx[ni] = n0 + wave * 64 + ni * 16 + lh;
    cok[ni] = cidx[ni] < N;
    w4[ni] = cok[ni] ? wsc[cidx[ni]] : 0.f;
    bi4[ni] = cok[ni] ? bias[cidx[ni]] : 0.f;
  }
  if (EPI == 0) {
#pragma unroll
    for (int mi = 0; mi < 4; ++mi) {
#pragma unroll
      for (int j = 0; j < 4; ++j) {
        const long long t = t0 + mi * 16 + (lane >> 4) * 4 + j;
        const bool valid = (t < M);
        const float st = valid ? scale_tok[t] : 0.f;
        float rowmax = 0.f;
#pragma unroll
        for (int ni = 0; ni < 4; ++ni) {
          float v = (float)acc[mi][ni][j] * st * w4[ni] + bi4[ni];
          v = __half2float(__float2half(v));  // fc1 rounds to fp16 (reference)
          const float gl = 0.5f * v * (1.f + erff(v * 0.70710678118654752f));
          rowmax = fmaxf(rowmax, fabsf(gl));
          if (valid && cok[ni]) gout[t * (long long)N + cidx[ni]] = __float2half(gl);
        }
#pragma unroll
        for (int m = 1; m < 16; m <<= 1) rowmax = fmaxf(rowmax, __shfl_xor(rowmax, m));
        if (valid && lh == 0) atomicMax(&amax[t], __float_as_uint(rowmax));
      }
    }
  } else {
#pragma unroll
    for (int mi = 0; mi < 4; ++mi) {
#pragma unroll
      for (int j = 0; j < 4; ++j) {
        const long long t = t0 + mi * 16 + (lane >> 4) * 4 + j;
        if (t < M) {
          const float am = __uint_as_float(amax[t]);
          const float st = __half2float(__float2half(am * (1.f / 127.f)));
#pragma unroll
          for (int ni = 0; ni < 4; ++ni) {
            const float v = (float)acc[mi][ni][j] * st * w4[ni] + bi4[ni];
            if (cok[ni]) fout[t * (long long)N + cidx[ni]] = __half2float(__float2half(v));
          }
        }
      }
    }
  }
}

// ---------------------------------------------------------------------------
// int32 -> int8 packing for x, w1, w2 (+ zero the amax buffer each call)
// ---------------------------------------------------------------------------
__global__ void pack_all(const int* __restrict__ a, const int* __restrict__ b,
                         const int* __restrict__ c,
                         signed char* __restrict__ pa, signed char* __restrict__ pb,
                         signed char* __restrict__ pc,
                         unsigned int* __restrict__ amax,
                         long long na, long long nb, long long nc, int T) {
  const long long gid = blockIdx.x * (long long)blockDim.x + threadIdx.x;
  if (gid < T) amax[gid] = 0u;
  const long long n4a = na >> 2, n4b = nb >> 2, n4c = nc >> 2;
  const long long tot = n4a + n4b + n4c;
  const long long stride = (long long)gridDim.x * blockDim.x;
  for (long long u = gid; u < tot; u += stride) {
    const int* src; signed char* dst; long long loc;
    if (u < n4a)            { src = a; dst = pa; loc = u; }
    else if (u < n4a + n4b) { src = b; dst = pb; loc = u - n4a; }
    else                    { src = c; dst = pc; loc = u - n4a - n4b; }
    const int4 v = *(const int4*)(src + (loc << 2));
    const unsigned out = (unsigned)(v.x & 0xff) | ((unsigned)(v.y & 0xff) << 8) |
                         ((unsigned)(v.z & 0xff) << 16) | ((unsigned)(v.w & 0xff) << 24);
    *(unsigned*)(dst + (loc << 2)) = out;
  }
}

// ---------------------------------------------------------------------------
// per-token dynamic int8 quantization of the GELU output
// ---------------------------------------------------------------------------
__global__ void gelu_quant(const __half* __restrict__ g, const unsigned int* __restrict__ amax,
                           signed char* __restrict__ q, long long total, int I) {
  const long long nchunk = total >> 3;
  const long long stride = (long long)gridDim.x * blockDim.x;
  for (long long c = blockIdx.x * (long long)blockDim.x + threadIdx.x; c < nchunk; c += stride) {
    const long long base = c << 3;  // 8 elems, never crosses a row (I % 8 == 0)
    const int t = (int)(base / I);
    const float am = __uint_as_float(amax[t]);
    const float s = fmaxf(__half2float(__float2half(am * (1.f / 127.f))), 1e-8f);
    const float inv = 1.f / s;
    const int4 raw = *(const int4*)(g + base);
    const __half2* h2 = (const __half2*)&raw;
    union { signed char b[8]; int2 v; } u;
#pragma unroll
    for (int k = 0; k < 4; ++k) {
      const float2 f = __half22float2(h2[k]);
      const float q0 = fminf(fmaxf(rintf(f.x * inv), -128.f), 127.f);
      const float q1 = fminf(fmaxf(rintf(f.y * inv), -128.f), 127.f);
      u.b[k * 2]     = (signed char)(int)q0;
      u.b[k * 2 + 1] = (signed char)(int)q1;
    }
    *(int2*)(q + base) = u.v;
  }
}

extern "C" void kernel_launch(void* const* d_in, const int* in_sizes, int n_in,
                              void* d_out, int out_size, void* d_ws, size_t ws_size,
                              hipStream_t stream) {
  const int* hs = (const int*)d_in[0];
  const float* scale_in = (const float*)d_in[1];   // fp16 in reference -> f32 buffer
  const int* w1 = (const int*)d_in[2];
  const float* w1s = (const float*)d_in[3];
  const float* b1 = (const float*)d_in[4];
  const int* w2 = (const int*)d_in[5];
  const float* w2s = (const float*)d_in[6];
  const float* b2 = (const float*)d_in[7];

  const int T = in_sizes[1];        // 2050
  const int I = in_sizes[3];        // 12800
  const int H = in_sizes[6];        // 3200

  char* ws = (char*)d_ws;
  unsigned int* amax = (unsigned int*)ws;                    // T u32 (16KB pad)
  signed char* px  = (signed char*)(ws + 16384);             // T*H
  signed char* pw1 = px + (size_t)T * H;                     // I*H
  signed char* pw2 = pw1 + (size_t)I * H;                    // H*I
  __half* gbuf = (__half*)(pw2 + (size_t)H * I);             // T*I fp16
  signed char* qbuf = (signed char*)(gbuf + (size_t)T * I);  // T*I

  const long long nx = (long long)T * H, nw1 = (long long)I * H, nw2 = (long long)H * I;

  pack_all<<<2048, 256, 0, stream>>>(hs, w1, w2, px, pw1, pw2, amax, nx, nw1, nw2, T);

  // fc1: 64x256 tiles, grid 50 x 33 = 1650 blocks, 4/CU
  dim3 g1(I / 256, (T + 63) / 64);
  gemm_w<0><<<g1, 256, 0, stream>>>(px, pw1, T, I, H, scale_in, w1s, b1, gbuf, amax, nullptr);

  gelu_quant<<<2048, 256, 0, stream>>>(gbuf, amax, qbuf, (long long)T * I, I);

  // fc2: 64x256 tiles, grid 13 x 33 = 429 blocks
  dim3 g2((H + 255) / 256, (T + 63) / 64);
  gemm_w<1><<<g2, 256, 0, stream>>>(qbuf, pw2, T, H, I, nullptr, w2s, b2, nullptr, amax, (float*)d_out);
}

// Round 10
// 409.850 us; speedup vs baseline: 1.0342x; 1.0342x over previous
//
#include <hip/hip_runtime.h>
#include <hip/hip_fp16.h>

typedef int v4i  __attribute__((ext_vector_type(4)));
typedef int v16i __attribute__((ext_vector_type(16)));

#define AS1C(p) ((const __attribute__((address_space(1))) void*)(p))
#define AS3(p)  ((__attribute__((address_space(3))) void*)(p))

// ---------------------------------------------------------------------------
// 128x128 int8 GEMM tile, C = A[M,K]*B[N,K]^T, 4 waves (2x2 of 64x64),
// mfma_i32_32x32x32_i8 (8 MFMA/iter/wave vs 16 with 16x16x64 — same ops,
// same ds_read bytes), double-buffered LDS (32KB), __syncthreads per K-step,
// hoisted staging pointers (no per-iter 64-bit address recompute).
// 16B-slot XOR swizzle on the global side; reader applies the involution.
// C/D layout: col=lane&31, row=(reg&3)+8*(reg>>2)+4*(lane>>5)  [m74/m101].
// EPI 0: fc1 (dequant+bias -> fp16 -> GELU -> gout fp16 + atomicMax amax)
// EPI 1: fc2 (dequant with fp16(amax/127)+bias -> fp16-rounded f32 out)
// ---------------------------------------------------------------------------
template <int EPI>
__launch_bounds__(256, 4)
__global__ void gemm32(const signed char* __restrict__ A, const signed char* __restrict__ Bw,
                       int M, int N, int K,
                       const float* __restrict__ scale_tok, const float* __restrict__ wsc,
                       const float* __restrict__ bias,
                       __half* __restrict__ gout, unsigned int* __restrict__ amax,
                       float* __restrict__ fout) {
  __shared__ __align__(16) char smem[2][16384];   // per buf: A 8KB | B 8KB
  const int tid = threadIdx.x;
  const int lane = tid & 63, wave = tid >> 6;
  const int wrow = (wave >> 1) * 64, wcol = (wave & 1) * 64;
  const int l31 = lane & 31, hi5 = lane >> 5;

  // column-chunked bijective XCD swizzle (r6-proven: big FETCH cut)
  const int gy = gridDim.y;
  int lid;
  {
    const int o = blockIdx.y * gridDim.x + blockIdx.x;
    const int nwg = gridDim.x * gy;
    const int q = nwg >> 3, r = nwg & 7;
    const int x = o & 7, p = o >> 3;
    lid = (x < r ? x * (q + 1) : r * (q + 1) + (x - r) * q) + p;
  }
  const long long t0 = (long long)(lid % gy) * 128;
  const long long n0 = (long long)(lid / gy) * 128;
  const int nk = K >> 6;
  const long long Mm1 = M - 1, Nm1 = N - 1;

  // ---- hoisted staging pointers: 4 chunks/wave (2 A + 2 B), 16B/lane
  const signed char* sp[4];
  int dst[4];
#pragma unroll
  for (int i = 0; i < 4; ++i) {
    const bool isA = i < 2;
    const int c = wave * 2 + (i & 1);             // chunk within A or B half
    const int rloc = c * 16 + (lane >> 2);        // tile-local row
    const int gslot = (((lane & 3) ^ ((rloc >> 1) & 3)) << 4);
    long long gr = (isA ? t0 : n0) + rloc;
    const long long rmax = isA ? Mm1 : Nm1;
    if (gr > rmax) gr = rmax;
    sp[i] = (isA ? A : Bw) + gr * (long long)K + gslot;
    dst[i] = (isA ? 0 : 8192) + c * 1024;
  }

#define STAGE(bi) do { \
    _Pragma("unroll") \
    for (int i = 0; i < 4; ++i) { \
      __builtin_amdgcn_global_load_lds(AS1C(sp[i]), AS3(&smem[bi][dst[i]]), 16, 0, 0); \
      sp[i] += 64; \
    } \
  } while (0)

  // ---- reader offsets: A-frag(mf,ks): row = wrow+mf*32+l31, seg = ks*2+hi5
  const int rA = wrow + l31, rB = wcol + l31;
  const int aswz = (rA >> 1) & 3, bswz = (rB >> 1) & 3;
  int offA[2][2], offB[2][2];
#pragma unroll
  for (int ks = 0; ks < 2; ++ks) {
    const int sa = ((ks * 2 + hi5) ^ aswz) << 4;
    const int sb = ((ks * 2 + hi5) ^ bswz) << 4;
#pragma unroll
    for (int mf = 0; mf < 2; ++mf) {
      offA[mf][ks] = (rA + mf * 32) * 64 + sa;
      offB[mf][ks] = 8192 + (rB + mf * 32) * 64 + sb;
    }
  }

  v16i acc[2][2] = {};

  STAGE(0);
  __syncthreads();

  int cur = 0;
  for (int kt = 0; kt < nk; ++kt) {
    if (kt + 1 < nk) STAGE(cur ^ 1);
    const char* base = smem[cur];
    v4i af[2][2], bf[2][2];
#pragma unroll
    for (int mf = 0; mf < 2; ++mf)
#pragma unroll
      for (int ks = 0; ks < 2; ++ks) {
        af[mf][ks] = *(const v4i*)(base + offA[mf][ks]);
        bf[mf][ks] = *(const v4i*)(base + offB[mf][ks]);
      }
#pragma unroll
    for (int ks = 0; ks < 2; ++ks)
#pragma unroll
      for (int mf = 0; mf < 2; ++mf)
#pragma unroll
        for (int nf = 0; nf < 2; ++nf)
          acc[mf][nf] = __builtin_amdgcn_mfma_i32_32x32x32_i8(af[mf][ks], bf[nf][ks], acc[mf][nf], 0, 0, 0);
    __syncthreads();
    cur ^= 1;
  }
#undef STAGE

  // ---- epilogue (C/D: col=lane&31, row=(reg&3)+8*(reg>>2)+4*hi5)
  long long cidx[2]; float w2[2], bi2[2]; bool cok[2];
#pragma unroll
  for (int nf = 0; nf < 2; ++nf) {
    cidx[nf] = n0 + wcol + nf * 32 + l31;
    cok[nf] = cidx[nf] < N;
    w2[nf] = cok[nf] ? wsc[cidx[nf]] : 0.f;
    bi2[nf] = cok[nf] ? bias[cidx[nf]] : 0.f;
  }
  if (EPI == 0) {
#pragma unroll
    for (int mf = 0; mf < 2; ++mf) {
#pragma unroll
      for (int reg = 0; reg < 16; ++reg) {
        const int row32 = (reg & 3) + 8 * (reg >> 2) + 4 * hi5;
        const long long t = t0 + wrow + mf * 32 + row32;
        const bool valid = t < M;
        const float st = valid ? scale_tok[t] : 0.f;
        float rowmax = 0.f;
#pragma unroll
        for (int nf = 0; nf < 2; ++nf) {
          float v = (float)acc[mf][nf][reg] * st * w2[nf] + bi2[nf];
          v = __half2float(__float2half(v));  // fc1 rounds to fp16 (reference)
          const float gl = 0.5f * v * (1.f + erff(v * 0.70710678118654752f));
          rowmax = fmaxf(rowmax, fabsf(gl));
          if (valid && cok[nf]) gout[t * (long long)N + cidx[nf]] = __float2half(gl);
        }
#pragma unroll
        for (int m = 1; m < 32; m <<= 1) rowmax = fmaxf(rowmax, __shfl_xor(rowmax, m));
        if (valid && l31 == 0) atomicMax(&amax[t], __float_as_uint(rowmax));
      }
    }
  } else {
#pragma unroll
    for (int mf = 0; mf < 2; ++mf) {
#pragma unroll
      for (int reg = 0; reg < 16; ++reg) {
        const int row32 = (reg & 3) + 8 * (reg >> 2) + 4 * hi5;
        const long long t = t0 + wrow + mf * 32 + row32;
        if (t < M) {
          const float am = __uint_as_float(amax[t]);
          const float st = __half2float(__float2half(am * (1.f / 127.f)));
#pragma unroll
          for (int nf = 0; nf < 2; ++nf) {
            const float v = (float)acc[mf][nf][reg] * st * w2[nf] + bi2[nf];
            if (cok[nf]) fout[t * (long long)N + cidx[nf]] = __half2float(__float2half(v));
          }
        }
      }
    }
  }
}

// ---------------------------------------------------------------------------
// int32 -> int8 packing for x, w1, w2 (+ zero the amax buffer each call)
// ---------------------------------------------------------------------------
__global__ void pack_all(const int* __restrict__ a, const int* __restrict__ b,
                         const int* __restrict__ c,
                         signed char* __restrict__ pa, signed char* __restrict__ pb,
                         signed char* __restrict__ pc,
                         unsigned int* __restrict__ amax,
                         long long na, long long nb, long long nc, int T) {
  const long long gid = blockIdx.x * (long long)blockDim.x + threadIdx.x;
  if (gid < T) amax[gid] = 0u;
  const long long n4a = na >> 2, n4b = nb >> 2, n4c = nc >> 2;
  const long long tot = n4a + n4b + n4c;
  const long long stride = (long long)gridDim.x * blockDim.x;
  for (long long u = gid; u < tot; u += stride) {
    const int* src; signed char* dst; long long loc;
    if (u < n4a)            { src = a; dst = pa; loc = u; }
    else if (u < n4a + n4b) { src = b; dst = pb; loc = u - n4a; }
    else                    { src = c; dst = pc; loc = u - n4a - n4b; }
    const int4 v = *(const int4*)(src + (loc << 2));
    const unsigned out = (unsigned)(v.x & 0xff) | ((unsigned)(v.y & 0xff) << 8) |
                         ((unsigned)(v.z & 0xff) << 16) | ((unsigned)(v.w & 0xff) << 24);
    *(unsigned*)(dst + (loc << 2)) = out;
  }
}

// ---------------------------------------------------------------------------
// per-token dynamic int8 quantization of the GELU output
// ---------------------------------------------------------------------------
__global__ void gelu_quant(const __half* __restrict__ g, const unsigned int* __restrict__ amax,
                           signed char* __restrict__ q, long long total, int I) {
  const long long nchunk = total >> 3;
  const long long stride = (long long)gridDim.x * blockDim.x;
  for (long long c = blockIdx.x * (long long)blockDim.x + threadIdx.x; c < nchunk; c += stride) {
    const long long base = c << 3;  // 8 elems, never crosses a row (I % 8 == 0)
    const int t = (int)(base / I);
    const float am = __uint_as_float(amax[t]);
    const float s = fmaxf(__half2float(__float2half(am * (1.f / 127.f))), 1e-8f);
    const float inv = 1.f / s;
    const int4 raw = *(const int4*)(g + base);
    const __half2* h2 = (const __half2*)&raw;
    union { signed char b[8]; int2 v; } u;
#pragma unroll
    for (int k = 0; k < 4; ++k) {
      const float2 f = __half22float2(h2[k]);
      const float q0 = fminf(fmaxf(rintf(f.x * inv), -128.f), 127.f);
      const float q1 = fminf(fmaxf(rintf(f.y * inv), -128.f), 127.f);
      u.b[k * 2]     = (signed char)(int)q0;
      u.b[k * 2 + 1] = (signed char)(int)q1;
    }
    *(int2*)(q + base) = u.v;
  }
}

extern "C" void kernel_launch(void* const* d_in, const int* in_sizes, int n_in,
                              void* d_out, int out_size, void* d_ws, size_t ws_size,
                              hipStream_t stream) {
  const int* hs = (const int*)d_in[0];
  const float* scale_in = (const float*)d_in[1];   // fp16 in reference -> f32 buffer
  const int* w1 = (const int*)d_in[2];
  const float* w1s = (const float*)d_in[3];
  const float* b1 = (const float*)d_in[4];
  const int* w2 = (const int*)d_in[5];
  const float* w2s = (const float*)d_in[6];
  const float* b2 = (const float*)d_in[7];

  const int T = in_sizes[1];        // 2050
  const int I = in_sizes[3];        // 12800
  const int H = in_sizes[6];        // 3200

  char* ws = (char*)d_ws;
  unsigned int* amax = (unsigned int*)ws;                    // T u32 (16KB pad)
  signed char* px  = (signed char*)(ws + 16384);             // T*H
  signed char* pw1 = px + (size_t)T * H;                     // I*H
  signed char* pw2 = pw1 + (size_t)I * H;                    // H*I
  __half* gbuf = (__half*)(pw2 + (size_t)H * I);             // T*I fp16
  signed char* qbuf = (signed char*)(gbuf + (size_t)T * I);  // T*I

  const long long nx = (long long)T * H, nw1 = (long long)I * H, nw2 = (long long)H * I;

  pack_all<<<2048, 256, 0, stream>>>(hs, w1, w2, px, pw1, pw2, amax, nx, nw1, nw2, T);

  // fc1: 128x128 tiles, grid 100 x 17 = 1700 blocks
  dim3 g1(I / 128, (T + 127) / 128);
  gemm32<0><<<g1, 256, 0, stream>>>(px, pw1, T, I, H, scale_in, w1s, b1, gbuf, amax, nullptr);

  gelu_quant<<<2048, 256, 0, stream>>>(gbuf, amax, qbuf, (long long)T * I, I);

  // fc2: 128x128 tiles, grid 25 x 17 = 425 blocks
  dim3 g2(H / 128, (T + 127) / 128);
  gemm32<1><<<g2, 256, 0, stream>>>(qbuf, pw2, T, H, I, nullptr, w2s, b2, nullptr, amax, (float*)d_out);
}

// Round 11
// 378.511 us; speedup vs baseline: 1.1198x; 1.0828x over previous
//
#include <hip/hip_runtime.h>
#include <hip/hip_fp16.h>

typedef int v4i __attribute__((ext_vector_type(4)));

#define AS1C(p) ((const __attribute__((address_space(1))) void*)(p))
#define AS3(p)  ((__attribute__((address_space(3))) void*)(p))
#define BARRIER() do { __builtin_amdgcn_s_barrier(); asm volatile("" ::: "memory"); } while (0)

// ---------------------------------------------------------------------------
// m201-faithful i8 GEMM: fat 16-MFMA phases, ring-4 LDS, depth-3 prefetch,
// counted vmcnt placed ONE PHASE BEFORE the tile's first ds_read (r4-verified
// placement), setprio around each 16-MFMA cluster, 2 barriers per phase.
// C = A[M,K]*B[N,K]^T, mfma_i32_16x16x64_i8, K-tile = 64B.
//  BM=256 (fc1): 8 waves 2Mx4N, wave 128x64, 2 phases/K-tile (mi0-3, mi4-7),
//                4 loads/thread/tile (2+2), steady fence vmcnt(8).
//  BM=128 (fc2): 8 waves 2Mx4N, wave 64x64, 1 phase/K-tile (16 MFMA),
//                3 loads/thread/tile, steady fence vmcnt(6).
// 16B-slot XOR swizzle, global-side, reader involution (0 conflicts r2-r9).
// EPI 0: fc1 (dequant+bias -> fp16 -> GELU -> gout fp16 + atomicMax amax)
// EPI 1: fc2 (dequant with fp16(amax/127)+bias -> fp16-rounded f32 out)
// ---------------------------------------------------------------------------
template <int EPI, int BM>
__launch_bounds__(512, 1)
__global__ void gemm_m201(const signed char* __restrict__ A, const signed char* __restrict__ Bw,
                          int M, int N, int K,
                          const float* __restrict__ scale_tok, const float* __restrict__ wsc,
                          const float* __restrict__ bias,
                          __half* __restrict__ gout, unsigned int* __restrict__ amax,
                          float* __restrict__ fout) {
  constexpr int ABYTES = BM * 64;            // 16K / 8K
  constexpr int TB = ABYTES + 16384;         // + B 16K -> 32K / 24K
  constexpr int L = TB / (512 * 16);         // loads per thread per tile: 4 / 3
  constexpr int MI = BM / 32;                // 8 / 4
  __shared__ __align__(16) char smem[4 * TB];

  const int tid = threadIdx.x;
  const int lane = tid & 63, wave = tid >> 6;
  const int wavem = wave >> 2, waven = wave & 3;
  const int lh = lane & 15;

  // column-chunked bijective XCD swizzle
  const int gy = gridDim.y;
  int lid;
  {
    const int o = blockIdx.y * gridDim.x + blockIdx.x;
    const int nwg = gridDim.x * gy;
    const int q = nwg >> 3, r = nwg & 7;
    const int x = o & 7, p = o >> 3;
    lid = (x < r ? x * (q + 1) : r * (q + 1) + (x - r) * q) + p;
  }
  const long long t0 = (long long)(lid % gy) * BM;
  const long long n0 = (long long)(lid / gy) * 256;
  const int nk = K >> 6;
  const long long Mm1 = M - 1, Nm1 = N - 1;

  // ---- staging pointers: L 1KB-chunks per wave (A chunks then B chunks)
  const signed char* sp[L];
  int dst[L];
#pragma unroll
  for (int i = 0; i < L; ++i) {
    const int c = wave * L + i;
    const bool isA = c < (ABYTES / 1024);
    const int lr = (isA ? c : c - ABYTES / 1024) * 16 + (lane >> 2);
    const int gslot = (((lane & 3) ^ ((lr >> 1) & 3)) << 4);
    long long gr = isA ? (t0 + lr) : (n0 + lr);
    const long long rmax = isA ? Mm1 : Nm1;
    if (gr > rmax) gr = rmax;
    sp[i] = (isA ? A : Bw) + gr * (long long)K + gslot;
    dst[i] = c * 1024;
  }

#define STG(sl, i) do { \
    __builtin_amdgcn_global_load_lds(AS1C(sp[i]), AS3(&smem[(sl) * TB + dst[i]]), 16, 0, 0); \
    sp[i] += 64; \
  } while (0)

  // ---- reader offsets (XOR involution)
  const int xs = (((lane >> 4) ^ ((lh >> 1) & 3)) << 4);
  const int offA = wavem * (BM / 2) * 64 + lh * 64 + xs;   // + mi*1024
  const int offB = ABYTES + waven * 4096 + lh * 64 + xs;   // + ni*1024

  v4i acc[MI][4] = {};
  v4i a_[4], b_[4];

#define MFMA16(AOFS) do { \
    __builtin_amdgcn_s_setprio(1); \
    _Pragma("unroll") \
    for (int mi = 0; mi < 4; ++mi) \
      _Pragma("unroll") \
      for (int ni = 0; ni < 4; ++ni) \
        acc[(AOFS) + mi][ni] = __builtin_amdgcn_mfma_i32_16x16x64_i8(a_[mi], b_[ni], acc[(AOFS) + mi][ni], 0, 0, 0); \
    __builtin_amdgcn_s_setprio(0); \
  } while (0)

  // fence ensuring tile t+1 is resident (placed in last phase of tile t)
#define FENCE_NEXT(T_) do { \
    if ((T_) + 1 < nk) { \
      if ((T_) + 3 < nk)      { if constexpr (BM == 256) asm volatile("s_waitcnt vmcnt(8)" ::: "memory"); \
                                else                     asm volatile("s_waitcnt vmcnt(6)" ::: "memory"); } \
      else if ((T_) + 2 < nk) { if constexpr (BM == 256) asm volatile("s_waitcnt vmcnt(4)" ::: "memory"); \
                                else                     asm volatile("s_waitcnt vmcnt(3)" ::: "memory"); } \
      else                    asm volatile("s_waitcnt vmcnt(0)" ::: "memory"); \
    } \
  } while (0)

  // ---- prologue: stage tiles 0,1,2; fence tile 0; barrier  (nk >= 4 here)
#pragma unroll
  for (int i = 0; i < L; ++i) STG(0, i);
#pragma unroll
  for (int i = 0; i < L; ++i) STG(1, i);
#pragma unroll
  for (int i = 0; i < L; ++i) STG(2, i);
  if constexpr (BM == 256) asm volatile("s_waitcnt vmcnt(8)" ::: "memory");
  else                     asm volatile("s_waitcnt vmcnt(6)" ::: "memory");
  BARRIER();

  for (int t = 0; t < nk; ++t) {
    const int sl = t & 3;
    const int slw = (t + 3) & 3;          // write slot = (t-1)&3, freed by trail barrier
    const char* base = &smem[sl * TB];
    const bool pf = (t + 3) < nk;

    if constexpr (BM == 256) {
      // ---- P0: reads a0-3,b0-3 | stage 2 | bar | 16 MFMA | bar
      a_[0] = *(const v4i*)(base + offA);
      a_[1] = *(const v4i*)(base + offA + 1024);
      a_[2] = *(const v4i*)(base + offA + 2048);
      a_[3] = *(const v4i*)(base + offA + 3072);
      b_[0] = *(const v4i*)(base + offB);
      b_[1] = *(const v4i*)(base + offB + 1024);
      b_[2] = *(const v4i*)(base + offB + 2048);
      b_[3] = *(const v4i*)(base + offB + 3072);
      if (pf) { STG(slw, 0); STG(slw, 1); }
      BARRIER();
      MFMA16(0);
      BARRIER();
      // ---- P1: reads a4-7 | stage 2 | fence(t+1) | bar | 16 MFMA | bar
      a_[0] = *(const v4i*)(base + offA + 4096);
      a_[1] = *(const v4i*)(base + offA + 5120);
      a_[2] = *(const v4i*)(base + offA + 6144);
      a_[3] = *(const v4i*)(base + offA + 7168);
      if (pf) { STG(slw, 2); STG(slw, 3); }
      FENCE_NEXT(t);
      BARRIER();
      MFMA16(4);
      BARRIER();
    } else {
      // ---- single phase: reads | stage 3 | fence(t+1) | bar | 16 MFMA | bar
      a_[0] = *(const v4i*)(base + offA);
      a_[1] = *(const v4i*)(base + offA + 1024);
      a_[2] = *(const v4i*)(base + offA + 2048);
      a_[3] = *(const v4i*)(base + offA + 3072);
      b_[0] = *(const v4i*)(base + offB);
      b_[1] = *(const v4i*)(base + offB + 1024);
      b_[2] = *(const v4i*)(base + offB + 2048);
      b_[3] = *(const v4i*)(base + offB + 3072);
      if (pf) { STG(slw, 0); STG(slw, 1); STG(slw, 2); }
      FENCE_NEXT(t);
      BARRIER();
      MFMA16(0);
      BARRIER();
    }
  }
#undef STG
#undef MFMA16
#undef FENCE_NEXT

  // ---- epilogue
  long long cidx[4]; float w4[4], bi4[4]; bool cok[4];
#pragma unroll
  for (int ni = 0; ni < 4; ++ni) {
    cidx[ni] = n0 + waven * 64 + ni * 16 + lh;
    cok[ni] = cidx[ni] < N;
    w4[ni] = cok[ni] ? wsc[cidx[ni]] : 0.f;
    bi4[ni] = cok[ni] ? bias[cidx[ni]] : 0.f;
  }
  if (EPI == 0) {
#pragma unroll
    for (int mi = 0; mi < MI; ++mi) {
#pragma unroll
      for (int j = 0; j < 4; ++j) {
        const long long t = t0 + wavem * (BM / 2) + mi * 16 + (lane >> 4) * 4 + j;
        const bool valid = t < M;
        const float st = valid ? scale_tok[t] : 0.f;
        float rowmax = 0.f;
#pragma unroll
        for (int ni = 0; ni < 4; ++ni) {
          float v = (float)acc[mi][ni][j] * st * w4[ni] + bi4[ni];
          v = __half2float(__float2half(v));  // fc1 rounds to fp16 (reference)
          const float gl = 0.5f * v * (1.f + erff(v * 0.70710678118654752f));
          rowmax = fmaxf(rowmax, fabsf(gl));
          if (valid && cok[ni]) gout[t * (long long)N + cidx[ni]] = __float2half(gl);
        }
#pragma unroll
        for (int m = 1; m < 16; m <<= 1) rowmax = fmaxf(rowmax, __shfl_xor(rowmax, m));
        if (valid && lh == 0) atomicMax(&amax[t], __float_as_uint(rowmax));
      }
    }
  } else {
#pragma unroll
    for (int mi = 0; mi < MI; ++mi) {
#pragma unroll
      for (int j = 0; j < 4; ++j) {
        const long long t = t0 + wavem * (BM / 2) + mi * 16 + (lane >> 4) * 4 + j;
        if (t < M) {
          const float am = __uint_as_float(amax[t]);
          const float st = __half2float(__float2half(am * (1.f / 127.f)));
#pragma unroll
          for (int ni = 0; ni < 4; ++ni) {
            const float v = (float)acc[mi][ni][j] * st * w4[ni] + bi4[ni];
            if (cok[ni]) fout[t * (long long)N + cidx[ni]] = __half2float(__float2half(v));
          }
        }
      }
    }
  }
}

// ---------------------------------------------------------------------------
// int32 -> int8 packing for x, w1, w2 (+ zero the amax buffer each call)
// ---------------------------------------------------------------------------
__global__ void pack_all(const int* __restrict__ a, const int* __restrict__ b,
                         const int* __restrict__ c,
                         signed char* __restrict__ pa, signed char* __restrict__ pb,
                         signed char* __restrict__ pc,
                         unsigned int* __restrict__ amax,
                         long long na, long long nb, long long nc, int T) {
  const long long gid = blockIdx.x * (long long)blockDim.x + threadIdx.x;
  if (gid < T) amax[gid] = 0u;
  const long long n4a = na >> 2, n4b = nb >> 2, n4c = nc >> 2;
  const long long tot = n4a + n4b + n4c;
  const long long stride = (long long)gridDim.x * blockDim.x;
  for (long long u = gid; u < tot; u += stride) {
    const int* src; signed char* dst; long long loc;
    if (u < n4a)            { src = a; dst = pa; loc = u; }
    else if (u < n4a + n4b) { src = b; dst = pb; loc = u - n4a; }
    else                    { src = c; dst = pc; loc = u - n4a - n4b; }
    const int4 v = *(const int4*)(src + (loc << 2));
    const unsigned out = (unsigned)(v.x & 0xff) | ((unsigned)(v.y & 0xff) << 8) |
                         ((unsigned)(v.z & 0xff) << 16) | ((unsigned)(v.w & 0xff) << 24);
    *(unsigned*)(dst + (loc << 2)) = out;
  }
}

// ---------------------------------------------------------------------------
// per-token dynamic int8 quantization of the GELU output
// ---------------------------------------------------------------------------
__global__ void gelu_quant(const __half* __restrict__ g, const unsigned int* __restrict__ amax,
                           signed char* __restrict__ q, long long total, int I) {
  const long long nchunk = total >> 3;
  const long long stride = (long long)gridDim.x * blockDim.x;
  for (long long c = blockIdx.x * (long long)blockDim.x + threadIdx.x; c < nchunk; c += stride) {
    const long long base = c << 3;  // 8 elems, never crosses a row (I % 8 == 0)
    const int t = (int)(base / I);
    const float am = __uint_as_float(amax[t]);
    const float s = fmaxf(__half2float(__float2half(am * (1.f / 127.f))), 1e-8f);
    const float inv = 1.f / s;
    const int4 raw = *(const int4*)(g + base);
    const __half2* h2 = (const __half2*)&raw;
    union { signed char b[8]; int2 v; } u;
#pragma unroll
    for (int k = 0; k < 4; ++k) {
      const float2 f = __half22float2(h2[k]);
      const float q0 = fminf(fmaxf(rintf(f.x * inv), -128.f), 127.f);
      const float q1 = fminf(fmaxf(rintf(f.y * inv), -128.f), 127.f);
      u.b[k * 2]     = (signed char)(int)q0;
      u.b[k * 2 + 1] = (signed char)(int)q1;
    }
    *(int2*)(q + base) = u.v;
  }
}

extern "C" void kernel_launch(void* const* d_in, const int* in_sizes, int n_in,
                              void* d_out, int out_size, void* d_ws, size_t ws_size,
                              hipStream_t stream) {
  const int* hs = (const int*)d_in[0];
  const float* scale_in = (const float*)d_in[1];   // fp16 in reference -> f32 buffer
  const int* w1 = (const int*)d_in[2];
  const float* w1s = (const float*)d_in[3];
  const float* b1 = (const float*)d_in[4];
  const int* w2 = (const int*)d_in[5];
  const float* w2s = (const float*)d_in[6];
  const float* b2 = (const float*)d_in[7];

  const int T = in_sizes[1];        // 2050
  const int I = in_sizes[3];        // 12800
  const int H = in_sizes[6];        // 3200

  char* ws = (char*)d_ws;
  unsigned int* amax = (unsigned int*)ws;                    // T u32 (16KB pad)
  signed char* px  = (signed char*)(ws + 16384);             // T*H
  signed char* pw1 = px + (size_t)T * H;                     // I*H
  signed char* pw2 = pw1 + (size_t)I * H;                    // H*I
  __half* gbuf = (__half*)(pw2 + (size_t)H * I);             // T*I fp16
  signed char* qbuf = (signed char*)(gbuf + (size_t)T * I);  // T*I

  const long long nx = (long long)T * H, nw1 = (long long)I * H, nw2 = (long long)H * I;

  pack_all<<<2048, 256, 0, stream>>>(hs, w1, w2, px, pw1, pw2, amax, nx, nw1, nw2, T);

  // fc1: 256x256 tiles, grid 50 x 9 = 450 blocks
  dim3 g1(I / 256, (T + 255) / 256);
  gemm_m201<0, 256><<<g1, 512, 0, stream>>>(px, pw1, T, I, H, scale_in, w1s, b1, gbuf, amax, nullptr);

  gelu_quant<<<2048, 256, 0, stream>>>(gbuf, amax, qbuf, (long long)T * I, I);

  // fc2: 128x256 tiles, grid 13 x 17 = 221 blocks
  dim3 g2((H + 255) / 256, (T + 127) / 128);
  gemm_m201<1, 128><<<g2, 512, 0, stream>>>(qbuf, pw2, T, H, I, nullptr, w2s, b2, nullptr, amax, (float*)d_out);
}